// Round 21
// baseline (52.087 us; speedup 1.0000x reference)
//
#include <hip/hip_runtime.h>
#include <stdint.h>

#define N_ANCH 65648
#define NCHUNK 65          // k_bins chunks of 1024 anchors
#define CHUNK  1024
#define NQ16   4103        // 65648/16
#define CAP    2048        // candidate capacity (LDS)
#define KBASE  0xBE800000u // sortable key of 0.25; fg scores >= 1/3 -> bins in [42,255]
#define NBATCH 32
#define TOPK   100
#define FT     1024        // k_sel threads

struct Ptrs { const float* cls[8]; const float* reg[8]; };

__constant__ int   c_off[9] = {0,25281,50562,56803,63044,64565,64926,65287,65648};
__constant__ int   c_sz[8]  = {159,159,79,79,39,19,19,19};
__constant__ float c_st[8]  = {4.f,4.f,8.f,8.f,16.f,32.f,32.f,32.f};
__constant__ float c_rf[8]  = {27.5f,35.5f,55.5f,71.5f,111.5f,191.5f,255.5f,319.5f};

// sortable key for the masked score of anchor n in batch b; 0 if background.
// EXACT same fp sequence as all passing rounds.
__device__ inline uint32_t anchor_key(const Ptrs& p, int b, int n) {
  int k = 0;
#pragma unroll
  for (int q = 1; q < 8; ++q) if (n >= c_off[q]) k = q;
  int local = n - c_off[k];
  int hw = c_sz[k] * c_sz[k];
  const float* c = p.cls[k] + (size_t)(b * 3) * hw + local;
  float l0 = c[0], l1 = c[(size_t)hw], l2 = c[(size_t)2 * hw];
  float m = l0; int cl = 0;
  if (l1 > m) { m = l1; cl = 1; }
  if (l2 > m) { m = l2; cl = 2; }
  if (cl == 0) return 0u;
  float s = 1.0f / (expf(l0 - m) + expf(l1 - m) + expf(l2 - m));
  return __float_as_uint(s) | 0x80000000u; // positive float -> monotonic uint
}

// K1 (WIDE, 2080 blocks — proven ~13 us, byte-identical to r16): u8 bins + u16 hist.
__global__ __launch_bounds__(256) void k_bins(Ptrs p, uint8_t* bins, uint16_t* hist) {
  int bid = blockIdx.x;
  int b = bid / NCHUNK, chunk = bid % NCHUNK;
  int t = threadIdx.x;
  __shared__ uint32_t lh[256];
  lh[t] = 0;
  __syncthreads();
  int n0 = chunk * CHUNK + t * 4;
  if (n0 < N_ANCH) {
    uchar4 v; uint8_t* vb = (uint8_t*)&v;
#pragma unroll
    for (int u = 0; u < 4; ++u) {
      uint32_t key = anchor_key(p, b, n0 + u);
      uint8_t bin = key ? (uint8_t)((key - KBASE) >> 16) : (uint8_t)0;
      vb[u] = bin;
      if (bin) atomicAdd(&lh[bin], 1u);        // LDS only
    }
    *(uchar4*)(bins + (size_t)b * N_ANCH + n0) = v;
  }
  __syncthreads();
  hist[((size_t)b * NCHUNK + chunk) * 256 + t] = (uint16_t)lh[t];
}

// K2 (32 blocks x 256 — r11-proven-cheap): ONE hist reduce per batch -> thr[b].
__global__ __launch_bounds__(256) void k_thresh(const uint16_t* hist, uint32_t* thr_arr) {
  int b = blockIdx.x, t = threadIdx.x;
  __shared__ uint32_t tot[256];
  __shared__ int s_thr;
  const uint16_t* hb = hist + (size_t)b * NCHUNK * 256;
  uint32_t v0 = 0, v1 = 0, v2 = 0, v3 = 0;
  int ch = 0;
  for (; ch + 4 <= NCHUNK; ch += 4) {          // 4 accumulators: independent loads
    v0 += hb[(ch + 0) * 256 + t];
    v1 += hb[(ch + 1) * 256 + t];
    v2 += hb[(ch + 2) * 256 + t];
    v3 += hb[(ch + 3) * 256 + t];
  }
  for (; ch < NCHUNK; ++ch) v0 += hb[ch * 256 + t];
  tot[t] = v0 + v1 + v2 + v3;
  __syncthreads();
  for (int d = 1; d < 256; d <<= 1) {          // inclusive suffix sum
    uint32_t add = (t + d < 256) ? tot[t + d] : 0u;
    __syncthreads();
    tot[t] += add;
    __syncthreads();
  }
  uint32_t suf = tot[t], sufn = (t < 255) ? tot[t + 1] : 0u;
  if (suf >= TOPK && sufn < TOPK) s_thr = t;   // exactly one setter
  if (t == 0 && tot[0] < TOPK) s_thr = 0;
  __syncthreads();
  if (t == 0) {
    int thr = s_thr; if (thr < 1) thr = 1;     // bin>=1 <=> foreground
    thr_arr[b] = (uint32_t)thr;
  }
}

// rank-selection with 8-deep batched LDS broadcast reads; s_all zero-padded to
// a multiple of 8 (zeros never outrank real keys).
template<int U>
__device__ inline void rank_select(const unsigned long long* s_all, int c, int c8, int t,
                                   unsigned long long* top) {
  unsigned long long mine[U]; int rk[U];
#pragma unroll
  for (int u = 0; u < U; ++u) {
    int i = t + u * FT;
    mine[u] = (i < c) ? s_all[i] : 0ull;
    rk[u] = 0;
  }
  for (int j = 0; j < c8; j += 8) {
    unsigned long long v0 = s_all[j+0], v1 = s_all[j+1], v2 = s_all[j+2], v3 = s_all[j+3];
    unsigned long long v4 = s_all[j+4], v5 = s_all[j+5], v6 = s_all[j+6], v7 = s_all[j+7];
#pragma unroll
    for (int u = 0; u < U; ++u) {
      rk[u] += (v0 > mine[u]) + (v1 > mine[u]) + (v2 > mine[u]) + (v3 > mine[u])
             + (v4 > mine[u]) + (v5 > mine[u]) + (v6 > mine[u]) + (v7 > mine[u]);
    }
  }
#pragma unroll
  for (int u = 0; u < U; ++u) {
    int i = t + u * FT;
    if (i < c && rk[u] < TOPK) top[rk[u]] = mine[u];   // unique u64s -> unique ranks
  }
}

// K3 (32 blocks x 1024): r16's k_sel MINUS the threshold phase (thr comes from
// k_thresh): bin scan -> exact keys -> rank-select -> decode -> mask NMS -> out.
__global__ __launch_bounds__(FT) void k_sel(Ptrs p, const uint8_t* bins,
                                            const uint32_t* thr_arr, float* out) {
  int b = blockIdx.x, t = threadIdx.x;
  __shared__ int s_idx[CAP];
  __shared__ unsigned long long s_all[CAP + 8];
  __shared__ unsigned long long top[TOPK];
  __shared__ float bx1[TOPK], by1[TOPK], bx2[TOPK], by2[TOPK], area[TOPK], sc[TOPK];
  __shared__ int cls_s[TOPK], keep[TOPK];
  __shared__ unsigned long long sup0[TOPK], sup1[TOPK];
  __shared__ unsigned long long s_km[2], s_km2[2];
  __shared__ uint32_t s_cnt;

  uint32_t thr = thr_arr[b];                   // scalar, L2-hit
  if (t == 0) s_cnt = 0;
  if (t < TOPK) top[t] = 0ull;
  __syncthreads();                             // B1

  // ---- scan 64KB bins (uint4 = 16 bins, 4 rounds/thread), collect indices ----
  {
    const uint4* bp = (const uint4*)(bins + (size_t)b * N_ANCH);
    for (int i = t; i < NQ16; i += FT) {
      uint4 v4 = bp[i];
      uint32_t ws[4] = { v4.x, v4.y, v4.z, v4.w };
#pragma unroll
      for (int w = 0; w < 4; ++w) {
        uint32_t wv = ws[w];
        if (!wv) continue;
#pragma unroll
        for (int u = 0; u < 4; ++u) {
          uint32_t bin = (wv >> (8 * u)) & 0xFFu;
          if (bin >= thr) {
            uint32_t q = atomicAdd(&s_cnt, 1u);
            if (q < CAP) s_idx[q] = i * 16 + w * 4 + u;
          }
        }
      }
    }
  }
  __syncthreads();                             // B2
  int c = (int)min(s_cnt, (uint32_t)CAP);
  int c8 = (c + 7) & ~7;

  // ---- exact keys only for c candidates (cls L2/L3-warm) ----
  for (int i = t; i < c; i += FT) {
    int n = s_idx[i];
    s_all[i] = ((unsigned long long)anchor_key(p, b, n) << 32) | (uint32_t)(~(uint32_t)n);
  }
  for (int i = c + t; i < c8; i += FT) s_all[i] = 0ull;   // pad
  __syncthreads();                             // B3

  if (c <= FT) rank_select<1>(s_all, c, c8, t, top);
  else         rank_select<2>(s_all, c, c8, t, top);
  __syncthreads();                             // B4

  // ---- decode top-100 ----
  if (t < TOPK) {
    int r = t;
    unsigned long long pk = top[r];
    if (pk == 0ull) {
      sc[r] = -1.f; cls_s[r] = 0; keep[r] = 0;
      bx1[r] = by1[r] = bx2[r] = by2[r] = 0.f; area[r] = 1.f;
    } else {
      uint32_t key = (uint32_t)(pk >> 32);
      int n = (int)(~(uint32_t)pk);
      float score = __uint_as_float(key & 0x7FFFFFFFu);
      int k2 = 0;
#pragma unroll
      for (int q = 1; q < 8; ++q) if (n >= c_off[q]) k2 = q;
      int local = n - c_off[k2];
      int w = c_sz[k2], hw = w * w;
      int i2 = local / w, j2 = local % w;
      const float* cp = p.cls[k2] + (size_t)(b * 3) * hw + local;
      float l0 = cp[0], l1 = cp[(size_t)hw], l2 = cp[(size_t)2 * hw];
      float m = l0; int cl = 0;
      if (l1 > m) { m = l1; cl = 1; }
      if (l2 > m) { m = l2; cl = 2; }
      const float* rp = p.reg[k2] + (size_t)(b * 4) * hw + local;
      float r0 = rp[0], r1 = rp[(size_t)hw], r2 = rp[(size_t)2 * hw], r3 = rp[(size_t)3 * hw];
      float st = c_st[k2], rf = c_rf[k2];
      float cx = (float)j2 * st + st * 0.5f;
      float cy = (float)i2 * st + st * 0.5f;
      float x1 = cx - r0 * rf, y1 = cy - r1 * rf;
      float x2 = cx + r2 * rf, y2 = cy + r3 * rf;
      sc[r] = score; cls_s[r] = cl;
      bx1[r] = x1; by1[r] = y1; bx2[r] = x2; by2[r] = y2;
      area[r] = (x2 - x1 + 1.0f) * (y2 - y1 + 1.0f);
      keep[r] = (score >= 0.35f && cl > 0) ? 1 : 0;
    }
  }
  __syncthreads();                             // B5

  // ---- NMS stage A: per-thread suppression rows + keep ballots ----
  if (t < TOPK) {
    float a1x = bx1[t], a1y = by1[t], a2x = bx2[t], a2y = by2[t], aA = area[t];
    unsigned long long m0 = 0, m1 = 0;
    for (int j = t + 1; j < TOPK; ++j) {
      float xmin = fmaxf(a1x, bx1[j]), ymin = fmaxf(a1y, by1[j]);
      float xmax = fminf(a2x, bx2[j]), ymax = fminf(a2y, by2[j]);
      float inter = fmaxf(xmax - xmin, 0.f) * fmaxf(ymax - ymin, 0.f);
      float iou = inter / (aA + area[j] - inter);
      if (iou > 0.5f) { if (j < 64) m0 |= 1ull << j; else m1 |= 1ull << (j - 64); }
    }
    sup0[t] = m0; sup1[t] = m1;
  }
  if (t < 64) {
    unsigned long long m = __ballot(keep[t] != 0);
    if (t == 0) s_km[0] = m;
  } else if (t < 128) {
    unsigned long long m = __ballot(t < TOPK && keep[t] != 0);
    if (t == 64) s_km[1] = m;
  }
  __syncthreads();                             // B6

  // ---- NMS stage B: bitset greedy with 8-row prefetch (thread 0) ----
  if (t == 0) {
    unsigned long long km0 = s_km[0], km1 = s_km[1];
    for (int i0 = 0; i0 < TOPK; i0 += 8) {
      unsigned long long a0[8], a1[8];
#pragma unroll
      for (int q = 0; q < 8; ++q) {
        int i = i0 + q;
        a0[q] = (i < TOPK) ? sup0[i] : 0ull;
        a1[q] = (i < TOPK) ? sup1[i] : 0ull;
      }
#pragma unroll
      for (int q = 0; q < 8; ++q) {
        int i = i0 + q;
        if (i < TOPK) {
          bool ki = (i < 64) ? ((km0 >> i) & 1) : ((km1 >> (i - 64)) & 1);
          if (ki) { km0 &= ~a0[q]; km1 &= ~a1[q]; }
        }
      }
    }
    s_km2[0] = km0; s_km2[1] = km1;
  }
  __syncthreads();                             // B7

  if (t < TOPK) {
    int r = t, o = b * TOPK + r;
    bool kp = (r < 64) ? ((s_km2[0] >> r) & 1) : ((s_km2[1] >> (r - 64)) & 1);
    out[o] = kp ? sc[r] : 0.f;                                  // scores
    out[NBATCH * TOPK + o] = kp ? (float)cls_s[r] : 0.f;        // classes
    float* ob = out + 2 * NBATCH * TOPK + (size_t)o * 4;        // boxes
    ob[0] = kp ? bx1[r] : 0.f;
    ob[1] = kp ? by1[r] : 0.f;
    ob[2] = kp ? bx2[r] : 0.f;
    ob[3] = kp ? by2[r] : 0.f;
    out[6 * NBATCH * TOPK + o] = kp ? 1.f : 0.f;                // keep
  }
}

extern "C" void kernel_launch(void* const* d_in, const int* in_sizes, int n_in,
                              void* d_out, int out_size, void* d_ws, size_t ws_size,
                              hipStream_t stream) {
  Ptrs p;
  // setup_inputs() dict order is INTERLEAVED: cls0, reg0, cls1, reg1, ...
  for (int i = 0; i < 8; ++i) {
    p.cls[i] = (const float*)d_in[2 * i];
    p.reg[i] = (const float*)d_in[2 * i + 1];
  }
  uint8_t*  bins    = (uint8_t*)d_ws;                            // 2,100,736 B
  uint16_t* hist    = (uint16_t*)((char*)d_ws + 2100736);        // 1,064,960 B
  uint32_t* thr_arr = (uint32_t*)((char*)d_ws + 3165696);        // 128 B
  float* out = (float*)d_out;

  k_bins<<<NBATCH * NCHUNK, 256, 0, stream>>>(p, bins, hist);
  k_thresh<<<NBATCH, 256, 0, stream>>>(hist, thr_arr);
  k_sel<<<NBATCH, FT, 0, stream>>>(p, bins, thr_arr, out);
}

// Round 22
// 47.879 us; speedup vs baseline: 1.0879x; 1.0879x over previous
//
#include <hip/hip_runtime.h>
#include <stdint.h>

#define N_ANCH 65648
#define NCHUNK 65          // k_bins chunks of 1024 anchors
#define CHUNK  1024
#define NQ16   4103        // 65648/16
#define CAP    2048        // candidate capacity (LDS)
#define KBASE  0xBE800000u // sortable key of 0.25; fg scores >= 1/3 -> bins in [42,255]
#define NBATCH 32
#define TOPK   100
#define FT     1024        // k_sel threads

struct Ptrs { const float* cls[8]; const float* reg[8]; };

__constant__ int   c_off[9] = {0,25281,50562,56803,63044,64565,64926,65287,65648};
__constant__ int   c_sz[8]  = {159,159,79,79,39,19,19,19};
__constant__ float c_st[8]  = {4.f,4.f,8.f,8.f,16.f,32.f,32.f,32.f};
__constant__ float c_rf[8]  = {27.5f,35.5f,55.5f,71.5f,111.5f,191.5f,255.5f,319.5f};

// sortable key for the masked score of anchor n in batch b; 0 if background.
// EXACT same fp sequence as all passing rounds.
__device__ inline uint32_t anchor_key(const Ptrs& p, int b, int n) {
  int k = 0;
#pragma unroll
  for (int q = 1; q < 8; ++q) if (n >= c_off[q]) k = q;
  int local = n - c_off[k];
  int hw = c_sz[k] * c_sz[k];
  const float* c = p.cls[k] + (size_t)(b * 3) * hw + local;
  float l0 = c[0], l1 = c[(size_t)hw], l2 = c[(size_t)2 * hw];
  float m = l0; int cl = 0;
  if (l1 > m) { m = l1; cl = 1; }
  if (l2 > m) { m = l2; cl = 2; }
  if (cl == 0) return 0u;
  float s = 1.0f / (expf(l0 - m) + expf(l1 - m) + expf(l2 - m));
  return __float_as_uint(s) | 0x80000000u; // positive float -> monotonic uint
}

// K1 (WIDE, 2080 blocks — proven ~13 us, byte-identical to r16): u8 bins + u16 hist.
__global__ __launch_bounds__(256) void k_bins(Ptrs p, uint8_t* bins, uint16_t* hist) {
  int bid = blockIdx.x;
  int b = bid / NCHUNK, chunk = bid % NCHUNK;
  int t = threadIdx.x;
  __shared__ uint32_t lh[256];
  lh[t] = 0;
  __syncthreads();
  int n0 = chunk * CHUNK + t * 4;
  if (n0 < N_ANCH) {
    uchar4 v; uint8_t* vb = (uint8_t*)&v;
#pragma unroll
    for (int u = 0; u < 4; ++u) {
      uint32_t key = anchor_key(p, b, n0 + u);
      uint8_t bin = key ? (uint8_t)((key - KBASE) >> 16) : (uint8_t)0;
      vb[u] = bin;
      if (bin) atomicAdd(&lh[bin], 1u);        // LDS only
    }
    *(uchar4*)(bins + (size_t)b * N_ANCH + n0) = v;
  }
  __syncthreads();
  hist[((size_t)b * NCHUNK + chunk) * 256 + t] = (uint16_t)lh[t];
}

// rank-selection with 8-deep batched LDS broadcast reads + WAVE SKIP: waves whose
// candidates are all zero (t >= c) skip the whole loop. s_all zero-padded.
template<int U>
__device__ inline void rank_select(const unsigned long long* s_all, int c, int c8, int t,
                                   unsigned long long* top) {
  unsigned long long mine[U]; int rk[U];
  unsigned long long live = 0;
#pragma unroll
  for (int u = 0; u < U; ++u) {
    int i = t + u * FT;
    mine[u] = (i < c) ? s_all[i] : 0ull;
    live |= mine[u];
    rk[u] = 0;
  }
  if (__ballot(live != 0ull)) {                // whole wave idle -> skip
    for (int j = 0; j < c8; j += 8) {
      unsigned long long v0 = s_all[j+0], v1 = s_all[j+1], v2 = s_all[j+2], v3 = s_all[j+3];
      unsigned long long v4 = s_all[j+4], v5 = s_all[j+5], v6 = s_all[j+6], v7 = s_all[j+7];
#pragma unroll
      for (int u = 0; u < U; ++u) {
        rk[u] += (v0 > mine[u]) + (v1 > mine[u]) + (v2 > mine[u]) + (v3 > mine[u])
               + (v4 > mine[u]) + (v5 > mine[u]) + (v6 > mine[u]) + (v7 > mine[u]);
      }
    }
  }
#pragma unroll
  for (int u = 0; u < U; ++u) {
    int i = t + u * FT;
    if (i < c && rk[u] < TOPK) top[rk[u]] = mine[u];   // unique u64s -> unique ranks
  }
}

// K2 (32 blocks x 1024): paired-u32 hist reduce -> wave-scan threshold -> bin scan
// -> exact keys -> wave-skip rank-select -> decode -> mask NMS.
__global__ __launch_bounds__(FT) void k_sel(Ptrs p, const uint8_t* bins,
                                            const uint16_t* hist, float* out) {
  int b = blockIdx.x, t = threadIdx.x;
  __shared__ uint32_t part2[8][128];
  __shared__ uint32_t tot[256];
  __shared__ int s_idx[CAP];
  __shared__ unsigned long long s_all[CAP + 8];
  __shared__ unsigned long long top[TOPK];
  __shared__ float bx1[TOPK], by1[TOPK], bx2[TOPK], by2[TOPK], area[TOPK], sc[TOPK];
  __shared__ int cls_s[TOPK], keep[TOPK];
  __shared__ unsigned long long sup0[TOPK], sup1[TOPK];
  __shared__ unsigned long long s_km[2], s_km2[2];
  __shared__ uint32_t s_cnt;
  __shared__ int s_thr;

  // ---- hist partial sums: 8 groups x 128 threads, u32 = two u16 counts.
  //      Per-half sums <= 9*1024 < 65536 -> packed add can't carry. Bit-identical
  //      totals to the scalar version.
  {
    const uint32_t* hb32 = (const uint32_t*)(hist + (size_t)b * NCHUNK * 256);
    int g = t >> 7, j = t & 127;
    uint32_t acc = 0;
    for (int ch = g; ch < NCHUNK; ch += 8) acc += hb32[ch * 128 + j];
    part2[g][j] = acc;
    if (t == 0) s_cnt = 0;
    if (t < TOPK) top[t] = 0ull;
  }
  __syncthreads();                             // B1
  if (t < 128) {
    uint32_t s = part2[0][t] + part2[1][t] + part2[2][t] + part2[3][t]
               + part2[4][t] + part2[5][t] + part2[6][t] + part2[7][t];
    tot[2 * t]     = s & 0xFFFFu;
    tot[2 * t + 1] = s >> 16;
  }
  __syncthreads();                             // B2

  // ---- threshold: single-wave suffix scan (wave 0, shfl ladder — r19-verified) ----
  if (t < 64) {
    int l = t;
    uint32_t t0 = tot[4 * l], t1 = tot[4 * l + 1], t2 = tot[4 * l + 2], t3 = tot[4 * l + 3];
    uint32_t s = t0 + t1 + t2 + t3;
    uint32_t S = s;
#pragma unroll
    for (int off = 1; off < 64; off <<= 1) {
      uint32_t v = __shfl_down(S, off);
      if (l + off < 64) S += v;
    }
    uint32_t total = __shfl(S, 0);
    uint32_t E = S - s;                        // suffix strictly after this lane
    uint32_t suf3 = t3 + E;
    uint32_t suf2 = t2 + suf3;
    uint32_t suf1 = t1 + suf2;
    uint32_t suf0 = S;
    if (total < TOPK) { if (l == 0) s_thr = 0; }
    else {
      if (suf0 >= TOPK && suf1 < TOPK) s_thr = 4 * l + 0;
      if (suf1 >= TOPK && suf2 < TOPK) s_thr = 4 * l + 1;
      if (suf2 >= TOPK && suf3 < TOPK) s_thr = 4 * l + 2;
      if (suf3 >= TOPK && E    < TOPK) s_thr = 4 * l + 3;
    }
  }
  __syncthreads();                             // B3
  uint32_t thr = (uint32_t)max(s_thr, 1);      // bin>=1 <=> foreground

  // ---- scan 64KB bins (uint4 = 16 bins, 4 rounds/thread), collect indices ----
  {
    const uint4* bp = (const uint4*)(bins + (size_t)b * N_ANCH);
    for (int i = t; i < NQ16; i += FT) {
      uint4 v4 = bp[i];
      uint32_t ws[4] = { v4.x, v4.y, v4.z, v4.w };
#pragma unroll
      for (int w = 0; w < 4; ++w) {
        uint32_t wv = ws[w];
        if (!wv) continue;
#pragma unroll
        for (int u = 0; u < 4; ++u) {
          uint32_t bin = (wv >> (8 * u)) & 0xFFu;
          if (bin >= thr) {
            uint32_t q = atomicAdd(&s_cnt, 1u);
            if (q < CAP) s_idx[q] = i * 16 + w * 4 + u;
          }
        }
      }
    }
  }
  __syncthreads();                             // B4
  int c = (int)min(s_cnt, (uint32_t)CAP);
  int c8 = (c + 7) & ~7;

  // ---- exact keys only for c candidates (cls L2/L3-warm) ----
  for (int i = t; i < c; i += FT) {
    int n = s_idx[i];
    s_all[i] = ((unsigned long long)anchor_key(p, b, n) << 32) | (uint32_t)(~(uint32_t)n);
  }
  for (int i = c + t; i < c8; i += FT) s_all[i] = 0ull;   // pad
  __syncthreads();                             // B5

  if (c <= FT) rank_select<1>(s_all, c, c8, t, top);
  else         rank_select<2>(s_all, c, c8, t, top);
  __syncthreads();                             // B6

  // ---- decode top-100 ----
  if (t < TOPK) {
    int r = t;
    unsigned long long pk = top[r];
    if (pk == 0ull) {
      sc[r] = -1.f; cls_s[r] = 0; keep[r] = 0;
      bx1[r] = by1[r] = bx2[r] = by2[r] = 0.f; area[r] = 1.f;
    } else {
      uint32_t key = (uint32_t)(pk >> 32);
      int n = (int)(~(uint32_t)pk);
      float score = __uint_as_float(key & 0x7FFFFFFFu);
      int k2 = 0;
#pragma unroll
      for (int q = 1; q < 8; ++q) if (n >= c_off[q]) k2 = q;
      int local = n - c_off[k2];
      int w = c_sz[k2], hw = w * w;
      int i2 = local / w, j2 = local % w;
      const float* cp = p.cls[k2] + (size_t)(b * 3) * hw + local;
      float l0 = cp[0], l1 = cp[(size_t)hw], l2 = cp[(size_t)2 * hw];
      float m = l0; int cl = 0;
      if (l1 > m) { m = l1; cl = 1; }
      if (l2 > m) { m = l2; cl = 2; }
      const float* rp = p.reg[k2] + (size_t)(b * 4) * hw + local;
      float r0 = rp[0], r1 = rp[(size_t)hw], r2 = rp[(size_t)2 * hw], r3 = rp[(size_t)3 * hw];
      float st = c_st[k2], rf = c_rf[k2];
      float cx = (float)j2 * st + st * 0.5f;
      float cy = (float)i2 * st + st * 0.5f;
      float x1 = cx - r0 * rf, y1 = cy - r1 * rf;
      float x2 = cx + r2 * rf, y2 = cy + r3 * rf;
      sc[r] = score; cls_s[r] = cl;
      bx1[r] = x1; by1[r] = y1; bx2[r] = x2; by2[r] = y2;
      area[r] = (x2 - x1 + 1.0f) * (y2 - y1 + 1.0f);
      keep[r] = (score >= 0.35f && cl > 0) ? 1 : 0;
    }
  }
  __syncthreads();                             // B7

  // ---- NMS stage A: per-thread suppression rows + keep ballots ----
  if (t < TOPK) {
    float a1x = bx1[t], a1y = by1[t], a2x = bx2[t], a2y = by2[t], aA = area[t];
    unsigned long long m0 = 0, m1 = 0;
    for (int j = t + 1; j < TOPK; ++j) {
      float xmin = fmaxf(a1x, bx1[j]), ymin = fmaxf(a1y, by1[j]);
      float xmax = fminf(a2x, bx2[j]), ymax = fminf(a2y, by2[j]);
      float inter = fmaxf(xmax - xmin, 0.f) * fmaxf(ymax - ymin, 0.f);
      float iou = inter / (aA + area[j] - inter);
      if (iou > 0.5f) { if (j < 64) m0 |= 1ull << j; else m1 |= 1ull << (j - 64); }
    }
    sup0[t] = m0; sup1[t] = m1;
  }
  if (t < 64) {
    unsigned long long m = __ballot(keep[t] != 0);
    if (t == 0) s_km[0] = m;
  } else if (t < 128) {
    unsigned long long m = __ballot(t < TOPK && keep[t] != 0);
    if (t == 64) s_km[1] = m;
  }
  __syncthreads();                             // B8

  // ---- NMS stage B: bitset greedy with 8-row prefetch (thread 0) ----
  if (t == 0) {
    unsigned long long km0 = s_km[0], km1 = s_km[1];
    for (int i0 = 0; i0 < TOPK; i0 += 8) {
      unsigned long long a0[8], a1[8];
#pragma unroll
      for (int q = 0; q < 8; ++q) {
        int i = i0 + q;
        a0[q] = (i < TOPK) ? sup0[i] : 0ull;
        a1[q] = (i < TOPK) ? sup1[i] : 0ull;
      }
#pragma unroll
      for (int q = 0; q < 8; ++q) {
        int i = i0 + q;
        if (i < TOPK) {
          bool ki = (i < 64) ? ((km0 >> i) & 1) : ((km1 >> (i - 64)) & 1);
          if (ki) { km0 &= ~a0[q]; km1 &= ~a1[q]; }
        }
      }
    }
    s_km2[0] = km0; s_km2[1] = km1;
  }
  __syncthreads();                             // B9

  if (t < TOPK) {
    int r = t, o = b * TOPK + r;
    bool kp = (r < 64) ? ((s_km2[0] >> r) & 1) : ((s_km2[1] >> (r - 64)) & 1);
    out[o] = kp ? sc[r] : 0.f;                                  // scores
    out[NBATCH * TOPK + o] = kp ? (float)cls_s[r] : 0.f;        // classes
    float* ob = out + 2 * NBATCH * TOPK + (size_t)o * 4;        // boxes
    ob[0] = kp ? bx1[r] : 0.f;
    ob[1] = kp ? by1[r] : 0.f;
    ob[2] = kp ? bx2[r] : 0.f;
    ob[3] = kp ? by2[r] : 0.f;
    out[6 * NBATCH * TOPK + o] = kp ? 1.f : 0.f;                // keep
  }
}

extern "C" void kernel_launch(void* const* d_in, const int* in_sizes, int n_in,
                              void* d_out, int out_size, void* d_ws, size_t ws_size,
                              hipStream_t stream) {
  Ptrs p;
  // setup_inputs() dict order is INTERLEAVED: cls0, reg0, cls1, reg1, ...
  for (int i = 0; i < 8; ++i) {
    p.cls[i] = (const float*)d_in[2 * i];
    p.reg[i] = (const float*)d_in[2 * i + 1];
  }
  uint8_t*  bins = (uint8_t*)d_ws;                               // 2,100,736 B
  uint16_t* hist = (uint16_t*)((char*)d_ws + 2100736);           // 1,064,960 B
  float* out = (float*)d_out;

  k_bins<<<NBATCH * NCHUNK, 256, 0, stream>>>(p, bins, hist);
  k_sel<<<NBATCH, FT, 0, stream>>>(p, bins, hist, out);
}

// Round 23
// 46.644 us; speedup vs baseline: 1.1167x; 1.0265x over previous
//
#include <hip/hip_runtime.h>
#include <stdint.h>

#define N_ANCH 65648
#define NCHUNK 65          // k_bins chunks of 1024 anchors
#define CHUNK  1024
#define NQ16   4103        // 65648/16
#define CAP    2048        // candidate capacity (LDS)
#define KBASE  0xBE800000u // sortable key of 0.25; fg scores >= 1/3 -> bins in [42,255]
#define NBATCH 32
#define TOPK   100
#define FT     1024        // k_sel threads

struct Ptrs { const float* cls[8]; const float* reg[8]; };

__constant__ int   c_off[9] = {0,25281,50562,56803,63044,64565,64926,65287,65648};
__constant__ int   c_sz[8]  = {159,159,79,79,39,19,19,19};
__constant__ float c_st[8]  = {4.f,4.f,8.f,8.f,16.f,32.f,32.f,32.f};
__constant__ float c_rf[8]  = {27.5f,35.5f,55.5f,71.5f,111.5f,191.5f,255.5f,319.5f};

// sortable key for the masked score of anchor n in batch b; 0 if background.
// EXACT same fp sequence as all passing rounds.
__device__ inline uint32_t anchor_key(const Ptrs& p, int b, int n) {
  int k = 0;
#pragma unroll
  for (int q = 1; q < 8; ++q) if (n >= c_off[q]) k = q;
  int local = n - c_off[k];
  int hw = c_sz[k] * c_sz[k];
  const float* c = p.cls[k] + (size_t)(b * 3) * hw + local;
  float l0 = c[0], l1 = c[(size_t)hw], l2 = c[(size_t)2 * hw];
  float m = l0; int cl = 0;
  if (l1 > m) { m = l1; cl = 1; }
  if (l2 > m) { m = l2; cl = 2; }
  if (cl == 0) return 0u;
  float s = 1.0f / (expf(l0 - m) + expf(l1 - m) + expf(l2 - m));
  return __float_as_uint(s) | 0x80000000u; // positive float -> monotonic uint
}

// K1 (WIDE, 2080 blocks): u8 bins + u16 hist. XCD-AFFINE remap: all 65 blocks of
// batch b run on XCD b%8 (round-robin bid%8 heuristic), so k_sel's block b (also
// XCD b%8) reads bins/hist/cls from LOCAL L2 instead of cross-XCD.
__global__ __launch_bounds__(256) void k_bins(Ptrs p, uint8_t* bins, uint16_t* hist) {
  int bid = blockIdx.x;
  int xcd = bid & 7;
  int s = bid >> 3;                  // [0, 260)
  int b = xcd + 8 * (s / NCHUNK);    // batches {xcd, xcd+8, xcd+16, xcd+24}
  int chunk = s % NCHUNK;
  int t = threadIdx.x;
  __shared__ uint32_t lh[256];
  lh[t] = 0;
  __syncthreads();
  int n0 = chunk * CHUNK + t * 4;
  if (n0 < N_ANCH) {
    uchar4 v; uint8_t* vb = (uint8_t*)&v;
#pragma unroll
    for (int u = 0; u < 4; ++u) {
      uint32_t key = anchor_key(p, b, n0 + u);
      uint8_t bin = key ? (uint8_t)((key - KBASE) >> 16) : (uint8_t)0;
      vb[u] = bin;
      if (bin) atomicAdd(&lh[bin], 1u);        // LDS only
    }
    *(uchar4*)(bins + (size_t)b * N_ANCH + n0) = v;
  }
  __syncthreads();
  hist[((size_t)b * NCHUNK + chunk) * 256 + t] = (uint16_t)lh[t];
}

// rank-selection with 8-deep batched LDS broadcast reads + WAVE SKIP (r22-proven).
template<int U>
__device__ inline void rank_select(const unsigned long long* s_all, int c, int c8, int t,
                                   unsigned long long* top) {
  unsigned long long mine[U]; int rk[U];
  unsigned long long live = 0;
#pragma unroll
  for (int u = 0; u < U; ++u) {
    int i = t + u * FT;
    mine[u] = (i < c) ? s_all[i] : 0ull;
    live |= mine[u];
    rk[u] = 0;
  }
  if (__ballot(live != 0ull)) {                // whole wave idle -> skip
    for (int j = 0; j < c8; j += 8) {
      unsigned long long v0 = s_all[j+0], v1 = s_all[j+1], v2 = s_all[j+2], v3 = s_all[j+3];
      unsigned long long v4 = s_all[j+4], v5 = s_all[j+5], v6 = s_all[j+6], v7 = s_all[j+7];
#pragma unroll
      for (int u = 0; u < U; ++u) {
        rk[u] += (v0 > mine[u]) + (v1 > mine[u]) + (v2 > mine[u]) + (v3 > mine[u])
               + (v4 > mine[u]) + (v5 > mine[u]) + (v6 > mine[u]) + (v7 > mine[u]);
      }
    }
  }
#pragma unroll
  for (int u = 0; u < U; ++u) {
    int i = t + u * FT;
    if (i < c && rk[u] < TOPK) top[rk[u]] = mine[u];   // unique u64s -> unique ranks
  }
}

// K2 (32 blocks x 1024): paired-u32 hist reduce -> wave-scan threshold -> bin scan
// -> exact keys -> wave-skip rank-select -> decode -> mask NMS. (r22 champion body)
__global__ __launch_bounds__(FT) void k_sel(Ptrs p, const uint8_t* bins,
                                            const uint16_t* hist, float* out) {
  int b = blockIdx.x, t = threadIdx.x;
  __shared__ uint32_t part2[8][128];
  __shared__ uint32_t tot[256];
  __shared__ int s_idx[CAP];
  __shared__ unsigned long long s_all[CAP + 8];
  __shared__ unsigned long long top[TOPK];
  __shared__ float bx1[TOPK], by1[TOPK], bx2[TOPK], by2[TOPK], area[TOPK], sc[TOPK];
  __shared__ int cls_s[TOPK], keep[TOPK];
  __shared__ unsigned long long sup0[TOPK], sup1[TOPK];
  __shared__ unsigned long long s_km[2], s_km2[2];
  __shared__ uint32_t s_cnt;
  __shared__ int s_thr;

  // ---- hist partial sums: 8 groups x 128 threads, u32 = two u16 counts ----
  {
    const uint32_t* hb32 = (const uint32_t*)(hist + (size_t)b * NCHUNK * 256);
    int g = t >> 7, j = t & 127;
    uint32_t acc = 0;
    for (int ch = g; ch < NCHUNK; ch += 8) acc += hb32[ch * 128 + j];
    part2[g][j] = acc;
    if (t == 0) s_cnt = 0;
    if (t < TOPK) top[t] = 0ull;
  }
  __syncthreads();                             // B1
  if (t < 128) {
    uint32_t s = part2[0][t] + part2[1][t] + part2[2][t] + part2[3][t]
               + part2[4][t] + part2[5][t] + part2[6][t] + part2[7][t];
    tot[2 * t]     = s & 0xFFFFu;
    tot[2 * t + 1] = s >> 16;
  }
  __syncthreads();                             // B2

  // ---- threshold: single-wave suffix scan (wave 0, shfl ladder) ----
  if (t < 64) {
    int l = t;
    uint32_t t0 = tot[4 * l], t1 = tot[4 * l + 1], t2 = tot[4 * l + 2], t3 = tot[4 * l + 3];
    uint32_t s = t0 + t1 + t2 + t3;
    uint32_t S = s;
#pragma unroll
    for (int off = 1; off < 64; off <<= 1) {
      uint32_t v = __shfl_down(S, off);
      if (l + off < 64) S += v;
    }
    uint32_t total = __shfl(S, 0);
    uint32_t E = S - s;                        // suffix strictly after this lane
    uint32_t suf3 = t3 + E;
    uint32_t suf2 = t2 + suf3;
    uint32_t suf1 = t1 + suf2;
    uint32_t suf0 = S;
    if (total < TOPK) { if (l == 0) s_thr = 0; }
    else {
      if (suf0 >= TOPK && suf1 < TOPK) s_thr = 4 * l + 0;
      if (suf1 >= TOPK && suf2 < TOPK) s_thr = 4 * l + 1;
      if (suf2 >= TOPK && suf3 < TOPK) s_thr = 4 * l + 2;
      if (suf3 >= TOPK && E    < TOPK) s_thr = 4 * l + 3;
    }
  }
  __syncthreads();                             // B3
  uint32_t thr = (uint32_t)max(s_thr, 1);      // bin>=1 <=> foreground

  // ---- scan 64KB bins (uint4 = 16 bins, 4 rounds/thread), collect indices ----
  {
    const uint4* bp = (const uint4*)(bins + (size_t)b * N_ANCH);
    for (int i = t; i < NQ16; i += FT) {
      uint4 v4 = bp[i];
      uint32_t ws[4] = { v4.x, v4.y, v4.z, v4.w };
#pragma unroll
      for (int w = 0; w < 4; ++w) {
        uint32_t wv = ws[w];
        if (!wv) continue;
#pragma unroll
        for (int u = 0; u < 4; ++u) {
          uint32_t bin = (wv >> (8 * u)) & 0xFFu;
          if (bin >= thr) {
            uint32_t q = atomicAdd(&s_cnt, 1u);
            if (q < CAP) s_idx[q] = i * 16 + w * 4 + u;
          }
        }
      }
    }
  }
  __syncthreads();                             // B4
  int c = (int)min(s_cnt, (uint32_t)CAP);
  int c8 = (c + 7) & ~7;

  // ---- exact keys only for c candidates (cls now LOCAL-L2-warm) ----
  for (int i = t; i < c; i += FT) {
    int n = s_idx[i];
    s_all[i] = ((unsigned long long)anchor_key(p, b, n) << 32) | (uint32_t)(~(uint32_t)n);
  }
  for (int i = c + t; i < c8; i += FT) s_all[i] = 0ull;   // pad
  __syncthreads();                             // B5

  if (c <= FT) rank_select<1>(s_all, c, c8, t, top);
  else         rank_select<2>(s_all, c, c8, t, top);
  __syncthreads();                             // B6

  // ---- decode top-100 ----
  if (t < TOPK) {
    int r = t;
    unsigned long long pk = top[r];
    if (pk == 0ull) {
      sc[r] = -1.f; cls_s[r] = 0; keep[r] = 0;
      bx1[r] = by1[r] = bx2[r] = by2[r] = 0.f; area[r] = 1.f;
    } else {
      uint32_t key = (uint32_t)(pk >> 32);
      int n = (int)(~(uint32_t)pk);
      float score = __uint_as_float(key & 0x7FFFFFFFu);
      int k2 = 0;
#pragma unroll
      for (int q = 1; q < 8; ++q) if (n >= c_off[q]) k2 = q;
      int local = n - c_off[k2];
      int w = c_sz[k2], hw = w * w;
      int i2 = local / w, j2 = local % w;
      const float* cp = p.cls[k2] + (size_t)(b * 3) * hw + local;
      float l0 = cp[0], l1 = cp[(size_t)hw], l2 = cp[(size_t)2 * hw];
      float m = l0; int cl = 0;
      if (l1 > m) { m = l1; cl = 1; }
      if (l2 > m) { m = l2; cl = 2; }
      const float* rp = p.reg[k2] + (size_t)(b * 4) * hw + local;
      float r0 = rp[0], r1 = rp[(size_t)hw], r2 = rp[(size_t)2 * hw], r3 = rp[(size_t)3 * hw];
      float st = c_st[k2], rf = c_rf[k2];
      float cx = (float)j2 * st + st * 0.5f;
      float cy = (float)i2 * st + st * 0.5f;
      float x1 = cx - r0 * rf, y1 = cy - r1 * rf;
      float x2 = cx + r2 * rf, y2 = cy + r3 * rf;
      sc[r] = score; cls_s[r] = cl;
      bx1[r] = x1; by1[r] = y1; bx2[r] = x2; by2[r] = y2;
      area[r] = (x2 - x1 + 1.0f) * (y2 - y1 + 1.0f);
      keep[r] = (score >= 0.35f && cl > 0) ? 1 : 0;
    }
  }
  __syncthreads();                             // B7

  // ---- NMS stage A: per-thread suppression rows + keep ballots ----
  if (t < TOPK) {
    float a1x = bx1[t], a1y = by1[t], a2x = bx2[t], a2y = by2[t], aA = area[t];
    unsigned long long m0 = 0, m1 = 0;
    for (int j = t + 1; j < TOPK; ++j) {
      float xmin = fmaxf(a1x, bx1[j]), ymin = fmaxf(a1y, by1[j]);
      float xmax = fminf(a2x, bx2[j]), ymax = fminf(a2y, by2[j]);
      float inter = fmaxf(xmax - xmin, 0.f) * fmaxf(ymax - ymin, 0.f);
      float iou = inter / (aA + area[j] - inter);
      if (iou > 0.5f) { if (j < 64) m0 |= 1ull << j; else m1 |= 1ull << (j - 64); }
    }
    sup0[t] = m0; sup1[t] = m1;
  }
  if (t < 64) {
    unsigned long long m = __ballot(keep[t] != 0);
    if (t == 0) s_km[0] = m;
  } else if (t < 128) {
    unsigned long long m = __ballot(t < TOPK && keep[t] != 0);
    if (t == 64) s_km[1] = m;
  }
  __syncthreads();                             // B8

  // ---- NMS stage B: bitset greedy with 8-row prefetch (thread 0) ----
  if (t == 0) {
    unsigned long long km0 = s_km[0], km1 = s_km[1];
    for (int i0 = 0; i0 < TOPK; i0 += 8) {
      unsigned long long a0[8], a1[8];
#pragma unroll
      for (int q = 0; q < 8; ++q) {
        int i = i0 + q;
        a0[q] = (i < TOPK) ? sup0[i] : 0ull;
        a1[q] = (i < TOPK) ? sup1[i] : 0ull;
      }
#pragma unroll
      for (int q = 0; q < 8; ++q) {
        int i = i0 + q;
        if (i < TOPK) {
          bool ki = (i < 64) ? ((km0 >> i) & 1) : ((km1 >> (i - 64)) & 1);
          if (ki) { km0 &= ~a0[q]; km1 &= ~a1[q]; }
        }
      }
    }
    s_km2[0] = km0; s_km2[1] = km1;
  }
  __syncthreads();                             // B9

  if (t < TOPK) {
    int r = t, o = b * TOPK + r;
    bool kp = (r < 64) ? ((s_km2[0] >> r) & 1) : ((s_km2[1] >> (r - 64)) & 1);
    out[o] = kp ? sc[r] : 0.f;                                  // scores
    out[NBATCH * TOPK + o] = kp ? (float)cls_s[r] : 0.f;        // classes
    float* ob = out + 2 * NBATCH * TOPK + (size_t)o * 4;        // boxes
    ob[0] = kp ? bx1[r] : 0.f;
    ob[1] = kp ? by1[r] : 0.f;
    ob[2] = kp ? bx2[r] : 0.f;
    ob[3] = kp ? by2[r] : 0.f;
    out[6 * NBATCH * TOPK + o] = kp ? 1.f : 0.f;                // keep
  }
}

extern "C" void kernel_launch(void* const* d_in, const int* in_sizes, int n_in,
                              void* d_out, int out_size, void* d_ws, size_t ws_size,
                              hipStream_t stream) {
  Ptrs p;
  // setup_inputs() dict order is INTERLEAVED: cls0, reg0, cls1, reg1, ...
  for (int i = 0; i < 8; ++i) {
    p.cls[i] = (const float*)d_in[2 * i];
    p.reg[i] = (const float*)d_in[2 * i + 1];
  }
  uint8_t*  bins = (uint8_t*)d_ws;                               // 2,100,736 B
  uint16_t* hist = (uint16_t*)((char*)d_ws + 2100736);           // 1,064,960 B
  float* out = (float*)d_out;

  k_bins<<<NBATCH * NCHUNK, 256, 0, stream>>>(p, bins, hist);
  k_sel<<<NBATCH, FT, 0, stream>>>(p, bins, hist, out);
}

// Round 24
// 46.205 us; speedup vs baseline: 1.1273x; 1.0095x over previous
//
#include <hip/hip_runtime.h>
#include <stdint.h>

#define N_ANCH 65648
#define NCHUNK 65          // k_bins chunks of 1024 anchors
#define CHUNK  1024
#define NQ16   4103        // 65648/16
#define CAP    2048        // candidate capacity (LDS)
#define KBASE  0xBE800000u // sortable key of 0.25; fg scores >= 1/3 -> bins in [42,255]
#define NBATCH 32
#define TOPK   100
#define FT     1024        // k_sel threads

struct Ptrs { const float* cls[8]; const float* reg[8]; };

__constant__ int   c_off[9] = {0,25281,50562,56803,63044,64565,64926,65287,65648};
__constant__ int   c_sz[8]  = {159,159,79,79,39,19,19,19};
__constant__ float c_st[8]  = {4.f,4.f,8.f,8.f,16.f,32.f,32.f,32.f};
__constant__ float c_rf[8]  = {27.5f,35.5f,55.5f,71.5f,111.5f,191.5f,255.5f,319.5f};

// sortable key for the masked score of anchor n in batch b; 0 if background.
// EXACT same fp sequence as all passing rounds. (Used by k_sel for exact keys.)
__device__ inline uint32_t anchor_key(const Ptrs& p, int b, int n) {
  int k = 0;
#pragma unroll
  for (int q = 1; q < 8; ++q) if (n >= c_off[q]) k = q;
  int local = n - c_off[k];
  int hw = c_sz[k] * c_sz[k];
  const float* c = p.cls[k] + (size_t)(b * 3) * hw + local;
  float l0 = c[0], l1 = c[(size_t)hw], l2 = c[(size_t)2 * hw];
  float m = l0; int cl = 0;
  if (l1 > m) { m = l1; cl = 1; }
  if (l2 > m) { m = l2; cl = 2; }
  if (cl == 0) return 0u;
  float s = 1.0f / (expf(l0 - m) + expf(l1 - m) + expf(l2 - m));
  return __float_as_uint(s) | 0x80000000u; // positive float -> monotonic uint
}

// K1 (WIDE, 2080 blocks, XCD-affine — r23): u8 bins + u16 hist.
// BRANCHLESS + LOAD-BATCHED inner: 12 independent plane loads issued together,
// then 12 exps; same fp ops per anchor -> bit-identical bins.
__global__ __launch_bounds__(256) void k_bins(Ptrs p, uint8_t* bins, uint16_t* hist) {
  int bid = blockIdx.x;
  int xcd = bid & 7;
  int s = bid >> 3;                  // [0, 260)
  int b = xcd + 8 * (s / NCHUNK);    // batches {xcd, xcd+8, xcd+16, xcd+24}
  int chunk = s % NCHUNK;
  int t = threadIdx.x;
  __shared__ uint32_t lh[256];
  lh[t] = 0;
  __syncthreads();
  int n0 = chunk * CHUNK + t * 4;
  if (n0 < N_ANCH) {                 // whole quad valid (65648 % 4 == 0)
    const float* base[4]; int hw4[4];
#pragma unroll
    for (int u = 0; u < 4; ++u) {
      int n = n0 + u, k = 0;
#pragma unroll
      for (int q = 1; q < 8; ++q) if (n >= c_off[q]) k = q;
      int hw = c_sz[k] * c_sz[k];
      base[u] = p.cls[k] + (size_t)(b * 3) * hw + (n - c_off[k]);
      hw4[u] = hw;
    }
    float l0[4], l1[4], l2[4];
#pragma unroll
    for (int u = 0; u < 4; ++u) l0[u] = base[u][0];
#pragma unroll
    for (int u = 0; u < 4; ++u) l1[u] = base[u][(size_t)hw4[u]];
#pragma unroll
    for (int u = 0; u < 4; ++u) l2[u] = base[u][(size_t)2 * hw4[u]];
    uchar4 v; uint8_t* vb = (uint8_t*)&v;
#pragma unroll
    for (int u = 0; u < 4; ++u) {
      float m = l0[u]; int cl = 0;
      if (l1[u] > m) { m = l1[u]; cl = 1; }
      if (l2[u] > m) { m = l2[u]; cl = 2; }
      float sc = 1.0f / (expf(l0[u] - m) + expf(l1[u] - m) + expf(l2[u] - m));
      uint32_t key = __float_as_uint(sc) | 0x80000000u;
      uint8_t bin = cl ? (uint8_t)((key - KBASE) >> 16) : (uint8_t)0;
      vb[u] = bin;
      if (bin) atomicAdd(&lh[bin], 1u);        // LDS only
    }
    *(uchar4*)(bins + (size_t)b * N_ANCH + n0) = v;
  }
  __syncthreads();
  hist[((size_t)b * NCHUNK + chunk) * 256 + t] = (uint16_t)lh[t];
}

// rank-selection with 8-deep batched LDS broadcast reads + WAVE SKIP (r22-proven).
template<int U>
__device__ inline void rank_select(const unsigned long long* s_all, int c, int c8, int t,
                                   unsigned long long* top) {
  unsigned long long mine[U]; int rk[U];
  unsigned long long live = 0;
#pragma unroll
  for (int u = 0; u < U; ++u) {
    int i = t + u * FT;
    mine[u] = (i < c) ? s_all[i] : 0ull;
    live |= mine[u];
    rk[u] = 0;
  }
  if (__ballot(live != 0ull)) {                // whole wave idle -> skip
    for (int j = 0; j < c8; j += 8) {
      unsigned long long v0 = s_all[j+0], v1 = s_all[j+1], v2 = s_all[j+2], v3 = s_all[j+3];
      unsigned long long v4 = s_all[j+4], v5 = s_all[j+5], v6 = s_all[j+6], v7 = s_all[j+7];
#pragma unroll
      for (int u = 0; u < U; ++u) {
        rk[u] += (v0 > mine[u]) + (v1 > mine[u]) + (v2 > mine[u]) + (v3 > mine[u])
               + (v4 > mine[u]) + (v5 > mine[u]) + (v6 > mine[u]) + (v7 > mine[u]);
      }
    }
  }
#pragma unroll
  for (int u = 0; u < U; ++u) {
    int i = t + u * FT;
    if (i < c && rk[u] < TOPK) top[rk[u]] = mine[u];   // unique u64s -> unique ranks
  }
}

// K2 (32 blocks x 1024 — r22/r23 champion body, unchanged).
__global__ __launch_bounds__(FT) void k_sel(Ptrs p, const uint8_t* bins,
                                            const uint16_t* hist, float* out) {
  int b = blockIdx.x, t = threadIdx.x;
  __shared__ uint32_t part2[8][128];
  __shared__ uint32_t tot[256];
  __shared__ int s_idx[CAP];
  __shared__ unsigned long long s_all[CAP + 8];
  __shared__ unsigned long long top[TOPK];
  __shared__ float bx1[TOPK], by1[TOPK], bx2[TOPK], by2[TOPK], area[TOPK], sc[TOPK];
  __shared__ int cls_s[TOPK], keep[TOPK];
  __shared__ unsigned long long sup0[TOPK], sup1[TOPK];
  __shared__ unsigned long long s_km[2], s_km2[2];
  __shared__ uint32_t s_cnt;
  __shared__ int s_thr;

  // ---- hist partial sums: 8 groups x 128 threads, u32 = two u16 counts ----
  {
    const uint32_t* hb32 = (const uint32_t*)(hist + (size_t)b * NCHUNK * 256);
    int g = t >> 7, j = t & 127;
    uint32_t acc = 0;
    for (int ch = g; ch < NCHUNK; ch += 8) acc += hb32[ch * 128 + j];
    part2[g][j] = acc;
    if (t == 0) s_cnt = 0;
    if (t < TOPK) top[t] = 0ull;
  }
  __syncthreads();                             // B1
  if (t < 128) {
    uint32_t s = part2[0][t] + part2[1][t] + part2[2][t] + part2[3][t]
               + part2[4][t] + part2[5][t] + part2[6][t] + part2[7][t];
    tot[2 * t]     = s & 0xFFFFu;
    tot[2 * t + 1] = s >> 16;
  }
  __syncthreads();                             // B2

  // ---- threshold: single-wave suffix scan (wave 0, shfl ladder) ----
  if (t < 64) {
    int l = t;
    uint32_t t0 = tot[4 * l], t1 = tot[4 * l + 1], t2 = tot[4 * l + 2], t3 = tot[4 * l + 3];
    uint32_t s = t0 + t1 + t2 + t3;
    uint32_t S = s;
#pragma unroll
    for (int off = 1; off < 64; off <<= 1) {
      uint32_t v = __shfl_down(S, off);
      if (l + off < 64) S += v;
    }
    uint32_t total = __shfl(S, 0);
    uint32_t E = S - s;                        // suffix strictly after this lane
    uint32_t suf3 = t3 + E;
    uint32_t suf2 = t2 + suf3;
    uint32_t suf1 = t1 + suf2;
    uint32_t suf0 = S;
    if (total < TOPK) { if (l == 0) s_thr = 0; }
    else {
      if (suf0 >= TOPK && suf1 < TOPK) s_thr = 4 * l + 0;
      if (suf1 >= TOPK && suf2 < TOPK) s_thr = 4 * l + 1;
      if (suf2 >= TOPK && suf3 < TOPK) s_thr = 4 * l + 2;
      if (suf3 >= TOPK && E    < TOPK) s_thr = 4 * l + 3;
    }
  }
  __syncthreads();                             // B3
  uint32_t thr = (uint32_t)max(s_thr, 1);      // bin>=1 <=> foreground

  // ---- scan 64KB bins (uint4 = 16 bins, 4 rounds/thread), collect indices ----
  {
    const uint4* bp = (const uint4*)(bins + (size_t)b * N_ANCH);
    for (int i = t; i < NQ16; i += FT) {
      uint4 v4 = bp[i];
      uint32_t ws[4] = { v4.x, v4.y, v4.z, v4.w };
#pragma unroll
      for (int w = 0; w < 4; ++w) {
        uint32_t wv = ws[w];
        if (!wv) continue;
#pragma unroll
        for (int u = 0; u < 4; ++u) {
          uint32_t bin = (wv >> (8 * u)) & 0xFFu;
          if (bin >= thr) {
            uint32_t q = atomicAdd(&s_cnt, 1u);
            if (q < CAP) s_idx[q] = i * 16 + w * 4 + u;
          }
        }
      }
    }
  }
  __syncthreads();                             // B4
  int c = (int)min(s_cnt, (uint32_t)CAP);
  int c8 = (c + 7) & ~7;

  // ---- exact keys only for c candidates (cls LOCAL-L2-warm) ----
  for (int i = t; i < c; i += FT) {
    int n = s_idx[i];
    s_all[i] = ((unsigned long long)anchor_key(p, b, n) << 32) | (uint32_t)(~(uint32_t)n);
  }
  for (int i = c + t; i < c8; i += FT) s_all[i] = 0ull;   // pad
  __syncthreads();                             // B5

  if (c <= FT) rank_select<1>(s_all, c, c8, t, top);
  else         rank_select<2>(s_all, c, c8, t, top);
  __syncthreads();                             // B6

  // ---- decode top-100 ----
  if (t < TOPK) {
    int r = t;
    unsigned long long pk = top[r];
    if (pk == 0ull) {
      sc[r] = -1.f; cls_s[r] = 0; keep[r] = 0;
      bx1[r] = by1[r] = bx2[r] = by2[r] = 0.f; area[r] = 1.f;
    } else {
      uint32_t key = (uint32_t)(pk >> 32);
      int n = (int)(~(uint32_t)pk);
      float score = __uint_as_float(key & 0x7FFFFFFFu);
      int k2 = 0;
#pragma unroll
      for (int q = 1; q < 8; ++q) if (n >= c_off[q]) k2 = q;
      int local = n - c_off[k2];
      int w = c_sz[k2], hw = w * w;
      int i2 = local / w, j2 = local % w;
      const float* cp = p.cls[k2] + (size_t)(b * 3) * hw + local;
      float l0 = cp[0], l1 = cp[(size_t)hw], l2 = cp[(size_t)2 * hw];
      float m = l0; int cl = 0;
      if (l1 > m) { m = l1; cl = 1; }
      if (l2 > m) { m = l2; cl = 2; }
      const float* rp = p.reg[k2] + (size_t)(b * 4) * hw + local;
      float r0 = rp[0], r1 = rp[(size_t)hw], r2 = rp[(size_t)2 * hw], r3 = rp[(size_t)3 * hw];
      float st = c_st[k2], rf = c_rf[k2];
      float cx = (float)j2 * st + st * 0.5f;
      float cy = (float)i2 * st + st * 0.5f;
      float x1 = cx - r0 * rf, y1 = cy - r1 * rf;
      float x2 = cx + r2 * rf, y2 = cy + r3 * rf;
      sc[r] = score; cls_s[r] = cl;
      bx1[r] = x1; by1[r] = y1; bx2[r] = x2; by2[r] = y2;
      area[r] = (x2 - x1 + 1.0f) * (y2 - y1 + 1.0f);
      keep[r] = (score >= 0.35f && cl > 0) ? 1 : 0;
    }
  }
  __syncthreads();                             // B7

  // ---- NMS stage A: per-thread suppression rows + keep ballots ----
  if (t < TOPK) {
    float a1x = bx1[t], a1y = by1[t], a2x = bx2[t], a2y = by2[t], aA = area[t];
    unsigned long long m0 = 0, m1 = 0;
    for (int j = t + 1; j < TOPK; ++j) {
      float xmin = fmaxf(a1x, bx1[j]), ymin = fmaxf(a1y, by1[j]);
      float xmax = fminf(a2x, bx2[j]), ymax = fminf(a2y, by2[j]);
      float inter = fmaxf(xmax - xmin, 0.f) * fmaxf(ymax - ymin, 0.f);
      float iou = inter / (aA + area[j] - inter);
      if (iou > 0.5f) { if (j < 64) m0 |= 1ull << j; else m1 |= 1ull << (j - 64); }
    }
    sup0[t] = m0; sup1[t] = m1;
  }
  if (t < 64) {
    unsigned long long m = __ballot(keep[t] != 0);
    if (t == 0) s_km[0] = m;
  } else if (t < 128) {
    unsigned long long m = __ballot(t < TOPK && keep[t] != 0);
    if (t == 64) s_km[1] = m;
  }
  __syncthreads();                             // B8

  // ---- NMS stage B: bitset greedy with 8-row prefetch (thread 0) ----
  if (t == 0) {
    unsigned long long km0 = s_km[0], km1 = s_km[1];
    for (int i0 = 0; i0 < TOPK; i0 += 8) {
      unsigned long long a0[8], a1[8];
#pragma unroll
      for (int q = 0; q < 8; ++q) {
        int i = i0 + q;
        a0[q] = (i < TOPK) ? sup0[i] : 0ull;
        a1[q] = (i < TOPK) ? sup1[i] : 0ull;
      }
#pragma unroll
      for (int q = 0; q < 8; ++q) {
        int i = i0 + q;
        if (i < TOPK) {
          bool ki = (i < 64) ? ((km0 >> i) & 1) : ((km1 >> (i - 64)) & 1);
          if (ki) { km0 &= ~a0[q]; km1 &= ~a1[q]; }
        }
      }
    }
    s_km2[0] = km0; s_km2[1] = km1;
  }
  __syncthreads();                             // B9

  if (t < TOPK) {
    int r = t, o = b * TOPK + r;
    bool kp = (r < 64) ? ((s_km2[0] >> r) & 1) : ((s_km2[1] >> (r - 64)) & 1);
    out[o] = kp ? sc[r] : 0.f;                                  // scores
    out[NBATCH * TOPK + o] = kp ? (float)cls_s[r] : 0.f;        // classes
    float* ob = out + 2 * NBATCH * TOPK + (size_t)o * 4;        // boxes
    ob[0] = kp ? bx1[r] : 0.f;
    ob[1] = kp ? by1[r] : 0.f;
    ob[2] = kp ? bx2[r] : 0.f;
    ob[3] = kp ? by2[r] : 0.f;
    out[6 * NBATCH * TOPK + o] = kp ? 1.f : 0.f;                // keep
  }
}

extern "C" void kernel_launch(void* const* d_in, const int* in_sizes, int n_in,
                              void* d_out, int out_size, void* d_ws, size_t ws_size,
                              hipStream_t stream) {
  Ptrs p;
  // setup_inputs() dict order is INTERLEAVED: cls0, reg0, cls1, reg1, ...
  for (int i = 0; i < 8; ++i) {
    p.cls[i] = (const float*)d_in[2 * i];
    p.reg[i] = (const float*)d_in[2 * i + 1];
  }
  uint8_t*  bins = (uint8_t*)d_ws;                               // 2,100,736 B
  uint16_t* hist = (uint16_t*)((char*)d_ws + 2100736);           // 1,064,960 B
  float* out = (float*)d_out;

  k_bins<<<NBATCH * NCHUNK, 256, 0, stream>>>(p, bins, hist);
  k_sel<<<NBATCH, FT, 0, stream>>>(p, bins, hist, out);
}